// Round 1
// baseline (1562.370 us; speedup 1.0000x reference)
//
#include <hip/hip_runtime.h>
#include <hip/hip_bf16.h>

typedef __attribute__((ext_vector_type(8))) short short8;
typedef __attribute__((ext_vector_type(4))) short short4v;
typedef __attribute__((ext_vector_type(4))) float f32x4;

static __device__ __forceinline__ ushort f2bf(float f) {
  union { __hip_bfloat16 h; ushort u; } cv;
  cv.h = __float2bfloat16(f);
  return cv.u;
}

// ---------------- fp32 -> bf16 convert, 8 elems/thread ----------------
__global__ __launch_bounds__(256) void cvt_bf16_k(const float* __restrict__ in,
                                                  ushort* __restrict__ out, int n8) {
  int i = blockIdx.x * 256 + threadIdx.x;
  if (i >= n8) return;
  const float4* p = (const float4*)in + (size_t)i * 2;
  float4 a = p[0], b = p[1];
  short8 o;
  o[0] = f2bf(a.x); o[1] = f2bf(a.y); o[2] = f2bf(a.z); o[3] = f2bf(a.w);
  o[4] = f2bf(b.x); o[5] = f2bf(b.y); o[6] = f2bf(b.z); o[7] = f2bf(b.w);
  ((short8*)out)[i] = o;
}

// ---------------- LayerNorm fp32 -> bf16 (C=2048, one row per block) ----------------
__global__ __launch_bounds__(256) void ln_k(const float* __restrict__ x, const float* __restrict__ w,
                                            const float* __restrict__ b, ushort* __restrict__ o) {
  const int row = blockIdx.x, t = threadIdx.x;
  const float* xr = x + (size_t)row * 2048;
  float4 v0 = *(const float4*)(xr + t * 4);
  float4 v1 = *(const float4*)(xr + t * 4 + 1024);
  float s  = v0.x + v0.y + v0.z + v0.w + v1.x + v1.y + v1.z + v1.w;
  float s2 = v0.x*v0.x + v0.y*v0.y + v0.z*v0.z + v0.w*v0.w
           + v1.x*v1.x + v1.y*v1.y + v1.z*v1.z + v1.w*v1.w;
  #pragma unroll
  for (int m = 32; m; m >>= 1) { s += __shfl_xor(s, m); s2 += __shfl_xor(s2, m); }
  __shared__ float red[8];
  const int lane = t & 63, wv = t >> 6;
  if (lane == 0) { red[wv * 2] = s; red[wv * 2 + 1] = s2; }
  __syncthreads();
  s  = red[0] + red[2] + red[4] + red[6];
  s2 = red[1] + red[3] + red[5] + red[7];
  const float mu = s * (1.f / 2048.f);
  const float rstd = rsqrtf(s2 * (1.f / 2048.f) - mu * mu + 1e-5f);
  float4 w0 = *(const float4*)(w + t * 4), w1 = *(const float4*)(w + t * 4 + 1024);
  float4 b0 = *(const float4*)(b + t * 4), b1 = *(const float4*)(b + t * 4 + 1024);
  short4v o0, o1;
  o0[0] = f2bf((v0.x - mu) * rstd * w0.x + b0.x);
  o0[1] = f2bf((v0.y - mu) * rstd * w0.y + b0.y);
  o0[2] = f2bf((v0.z - mu) * rstd * w0.z + b0.z);
  o0[3] = f2bf((v0.w - mu) * rstd * w0.w + b0.w);
  o1[0] = f2bf((v1.x - mu) * rstd * w1.x + b1.x);
  o1[1] = f2bf((v1.y - mu) * rstd * w1.y + b1.y);
  o1[2] = f2bf((v1.z - mu) * rstd * w1.z + b1.z);
  o1[3] = f2bf((v1.w - mu) * rstd * w1.w + b1.w);
  *(short4v*)(o + (size_t)row * 2048 + t * 4) = o0;
  *(short4v*)(o + (size_t)row * 2048 + t * 4 + 1024) = o1;
}

// ---------------- bf16 GEMM: C[M,N] = A[M,K] @ B[N,K]^T (+bias, epilogues) ----------------
// EPI 0: out bf16 = acc+bias       (qkv)
// EPI 1: out f32  = res + acc+bias (attn out-proj + residual)
// EPI 2: out bf16 = gelu(acc+bias) (fc1)
// EPI 3: out f32 += acc+bias       (fc2, in-place residual add on d_out)
template <int EPI>
__global__ __launch_bounds__(256) void gemm_bt_k(const ushort* __restrict__ A, const ushort* __restrict__ B,
                                                 const float* __restrict__ bias, const float* __restrict__ res,
                                                 void* __restrict__ outp, int M, int N, int K) {
  __shared__ char ldsA[128 * 128];  // 128 rows x 64 bf16 (128B/row), XOR-swizzled
  __shared__ char ldsB[128 * 128];
  const int nbn = N >> 7;
  const int bm = blockIdx.x / nbn, bn = blockIdx.x % nbn;
  const int t = threadIdx.x, lane = t & 63, w = t >> 6;
  const int wr = w >> 1, wc = w & 1;
  const int m0 = bm << 7, n0 = bn << 7;
  const int hi = lane >> 4, lo = lane & 15;
  f32x4 acc[4][4] = {};
  for (int k0 = 0; k0 < K; k0 += 64) {
    __syncthreads();
    #pragma unroll
    for (int j = 0; j < 4; j++) {
      const int chunk = j * 256 + t;
      const int row = chunk >> 3, c8 = chunk & 7;
      const int loff = row * 128 + ((c8 * 16) ^ ((row & 7) << 4));
      *(short8*)(ldsA + loff) = *(const short8*)(A + (size_t)(m0 + row) * K + k0 + c8 * 8);
      *(short8*)(ldsB + loff) = *(const short8*)(B + (size_t)(n0 + row) * K + k0 + c8 * 8);
    }
    __syncthreads();
    #pragma unroll
    for (int kk = 0; kk < 2; kk++) {
      const int cb = kk * 64 + hi * 16;
      short8 af[4], bfr[4];
      #pragma unroll
      for (int m = 0; m < 4; m++) {
        const int row = wr * 64 + m * 16 + lo;
        af[m] = *(const short8*)(ldsA + row * 128 + (cb ^ ((row & 7) << 4)));
      }
      #pragma unroll
      for (int n = 0; n < 4; n++) {
        const int row = wc * 64 + n * 16 + lo;
        bfr[n] = *(const short8*)(ldsB + row * 128 + (cb ^ ((row & 7) << 4)));
      }
      #pragma unroll
      for (int m = 0; m < 4; m++)
        #pragma unroll
        for (int n = 0; n < 4; n++)
          acc[m][n] = __builtin_amdgcn_mfma_f32_16x16x32_bf16(af[m], bfr[n], acc[m][n], 0, 0, 0);
    }
  }
  #pragma unroll
  for (int m = 0; m < 4; m++) {
    const int grow = m0 + wr * 64 + m * 16 + hi * 4;
    #pragma unroll
    for (int n = 0; n < 4; n++) {
      const int gcol = n0 + wc * 64 + n * 16 + lo;
      const float bv = bias[gcol];
      #pragma unroll
      for (int r = 0; r < 4; r++) {
        const size_t idx = (size_t)(grow + r) * N + gcol;
        float v = acc[m][n][r] + bv;
        if constexpr (EPI == 0) ((ushort*)outp)[idx] = f2bf(v);
        else if constexpr (EPI == 1) ((float*)outp)[idx] = res[idx] + v;
        else if constexpr (EPI == 2) ((ushort*)outp)[idx] = f2bf(0.5f * v * (1.f + erff(v * 0.70710678118f)));
        else ((float*)outp)[idx] += v;
      }
    }
  }
}

// ---------------- causal flash attention ----------------
// qkv: [B*T, 6144] bf16 (q|k|v each 2048, head h at h*128). out: [B*T, 2048] bf16.
// grid (16 qblocks, 128 bh), 256 thr: 4 waves x 16 q-rows, KV tiles of 64.
__global__ __launch_bounds__(256) void attn_k(const ushort* __restrict__ qkv, ushort* __restrict__ o) {
  const int qb = blockIdx.x;
  const int bh = blockIdx.y;
  const int bb = bh >> 4, h = bh & 15;
  const int t = threadIdx.x, lane = t & 63, w = t >> 6;
  const int hi = lane >> 4, lo = lane & 15;
  __shared__ char ldsK[64 * 256];    // [kv][d] 64x128 bf16, swizzled
  __shared__ char ldsV[128 * 128];   // transposed [d][kv] 128x64 bf16, swizzled
  __shared__ char ldsP[4][16 * 128]; // per-wave P tile 16x64 bf16, swizzled
  const size_t base = (size_t)bb * 1024 * 6144;
  const int qrow_a = qb * 64 + w * 16 + lo;  // A-operand row for QK^T
  short8 qf[4];
  #pragma unroll
  for (int kk = 0; kk < 4; kk++)
    qf[kk] = *(const short8*)(qkv + base + (size_t)qrow_a * 6144 + h * 128 + kk * 32 + hi * 8);
  float ms[4], ls[4];
  f32x4 oacc[8] = {};
  #pragma unroll
  for (int r = 0; r < 4; r++) { ms[r] = -1e30f; ls[r] = 0.f; }
  const int wave_qmax = qb * 64 + w * 16 + 15;
  for (int kv0 = 0; kv0 <= qb * 64; kv0 += 64) {
    __syncthreads();
    #pragma unroll
    for (int j = 0; j < 4; j++) {
      const int chunk = j * 256 + t;
      const int r = chunk >> 4, c8 = chunk & 15;
      const size_t grow = base + (size_t)(kv0 + r) * 6144 + h * 128 + c8 * 8;
      *(short8*)(ldsK + r * 256 + ((c8 * 16) ^ ((r & 7) << 4))) = *(const short8*)(qkv + grow + 2048);
      short8 vv = *(const short8*)(qkv + grow + 4096);
      #pragma unroll
      for (int e = 0; e < 8; e++) {
        const int d = c8 * 8 + e;
        *(short*)(ldsV + d * 128 + ((r * 2) ^ ((d & 7) << 4))) = vv[e];
      }
    }
    __syncthreads();
    if (kv0 > wave_qmax) continue;  // all barriers already passed; safe skip
    // S = Q K^T for 16x64 tile
    f32x4 s[4];
    #pragma unroll
    for (int nb = 0; nb < 4; nb++) {
      f32x4 z = {};
      const int krow = nb * 16 + lo;
      #pragma unroll
      for (int kk = 0; kk < 4; kk++) {
        const int cb = kk * 64 + hi * 16;
        short8 kf = *(const short8*)(ldsK + krow * 256 + (cb ^ ((krow & 7) << 4)));
        z = __builtin_amdgcn_mfma_f32_16x16x32_bf16(qf[kk], kf, z, 0, 0, 0);
      }
      s[nb] = z;
    }
    // online softmax (rows hi*4+r, cols distributed across lo lanes)
    float corr[4];
    #pragma unroll
    for (int r = 0; r < 4; r++) {
      const int qrow = qb * 64 + w * 16 + hi * 4 + r;
      float mx = -1e30f;
      #pragma unroll
      for (int nb = 0; nb < 4; nb++) {
        const int kcol = kv0 + nb * 16 + lo;
        float sv = s[nb][r] * 0.08838834764831845f;
        sv = (kcol <= qrow) ? sv : -1e30f;
        s[nb][r] = sv;
        mx = fmaxf(mx, sv);
      }
      #pragma unroll
      for (int msk = 1; msk < 16; msk <<= 1) mx = fmaxf(mx, __shfl_xor(mx, msk));
      const float mnew = fmaxf(ms[r], mx);
      corr[r] = __expf(ms[r] - mnew);
      ms[r] = mnew;
      float rs = 0.f;
      #pragma unroll
      for (int nb = 0; nb < 4; nb++) {
        const float p = __expf(s[nb][r] - mnew);
        s[nb][r] = p; rs += p;
      }
      #pragma unroll
      for (int msk = 1; msk < 16; msk <<= 1) rs += __shfl_xor(rs, msk);
      ls[r] = ls[r] * corr[r] + rs;
    }
    #pragma unroll
    for (int nf = 0; nf < 8; nf++)
      #pragma unroll
      for (int r = 0; r < 4; r++) oacc[nf][r] *= corr[r];
    // P -> LDS (bf16), then PV
    #pragma unroll
    for (int r = 0; r < 4; r++) {
      const int prow = hi * 4 + r;
      #pragma unroll
      for (int nb = 0; nb < 4; nb++) {
        const int pcol = nb * 16 + lo;
        *(short*)(ldsP[w] + prow * 128 + ((pcol * 2) ^ ((prow & 7) << 4))) = (short)f2bf(s[nb][r]);
      }
    }
    #pragma unroll
    for (int ks = 0; ks < 2; ks++) {
      const int acb = ks * 64 + hi * 16;
      short8 pf = *(const short8*)(ldsP[w] + lo * 128 + (acb ^ ((lo & 7) << 4)));
      #pragma unroll
      for (int nf = 0; nf < 8; nf++) {
        const int vrow = nf * 16 + lo;
        short8 vf = *(const short8*)(ldsV + vrow * 128 + (acb ^ ((vrow & 7) << 4)));
        oacc[nf] = __builtin_amdgcn_mfma_f32_16x16x32_bf16(pf, vf, oacc[nf], 0, 0, 0);
      }
    }
  }
  #pragma unroll
  for (int r = 0; r < 4; r++) {
    const float inv = 1.f / ls[r];
    const int qrow = qb * 64 + w * 16 + hi * 4 + r;
    ushort* orow = o + ((size_t)(bb * 1024 + qrow)) * 2048 + h * 128;
    #pragma unroll
    for (int nf = 0; nf < 8; nf++)
      orow[nf * 16 + lo] = f2bf(oacc[nf][r] * inv);
  }
}

extern "C" void kernel_launch(void* const* d_in, const int* in_sizes, int n_in,
                              void* d_out, int out_size, void* d_ws, size_t ws_size,
                              hipStream_t stream) {
  const float* x     = (const float*)d_in[0];
  const float* ln1w  = (const float*)d_in[1];
  const float* ln1b  = (const float*)d_in[2];
  const float* qkvw  = (const float*)d_in[3];
  const float* qkvb  = (const float*)d_in[4];
  const float* outw  = (const float*)d_in[5];
  const float* outb  = (const float*)d_in[6];
  const float* ln2w  = (const float*)d_in[7];
  const float* ln2b  = (const float*)d_in[8];
  const float* fc1w  = (const float*)d_in[9];
  const float* fc1b  = (const float*)d_in[10];
  const float* fc2w  = (const float*)d_in[11];
  const float* fc2b  = (const float*)d_in[12];
  float* out = (float*)d_out;

  char* ws = (char*)d_ws;
  // ws layout (total 256 MiB):
  ushort* qkvw_bf = (ushort*)(ws);               // 3*2048*2048 bf16 = 25165824 B
  ushort* outw_bf = (ushort*)(ws + 25165824);    // 2048*2048       =  8388608 B
  ushort* fc1w_bf = (ushort*)(ws + 33554432);    // 8192*2048       = 33554432 B
  ushort* fc2w_bf = (ushort*)(ws + 67108864);    // 2048*8192       = 33554432 B
  ushort* bufA    = (ushort*)(ws + 100663296);   // 8192*2048 bf16: xhat1 -> attnout -> xhat2
  ushort* bufR    = (ushort*)(ws + 134217728);   // 8192*8192 bf16 max: qkv -> gelu-h

  // weights fp32 -> bf16
  cvt_bf16_k<<<6144, 256, 0, stream>>>(qkvw, qkvw_bf, 12582912 / 8);
  cvt_bf16_k<<<2048, 256, 0, stream>>>(outw, outw_bf, 4194304 / 8);
  cvt_bf16_k<<<8192, 256, 0, stream>>>(fc1w, fc1w_bf, 16777216 / 8);
  cvt_bf16_k<<<8192, 256, 0, stream>>>(fc2w, fc2w_bf, 16777216 / 8);

  // LN1
  ln_k<<<8192, 256, 0, stream>>>(x, ln1w, ln1b, bufA);
  // QKV: [8192,2048] x [6144,2048]^T -> bf16 [8192,6144]
  gemm_bt_k<0><<<64 * 48, 256, 0, stream>>>(bufA, qkvw_bf, qkvb, nullptr, bufR, 8192, 6144, 2048);
  // attention -> bufA [8192,2048] bf16
  attn_k<<<dim3(16, 128), 256, 0, stream>>>(bufR, bufA);
  // out-proj + residual -> d_out fp32
  gemm_bt_k<1><<<64 * 16, 256, 0, stream>>>(bufA, outw_bf, outb, x, out, 8192, 2048, 2048);
  // LN2 (reads d_out)
  ln_k<<<8192, 256, 0, stream>>>(out, ln2w, ln2b, bufA);
  // FC1 + GELU -> bf16 [8192,8192]
  gemm_bt_k<2><<<64 * 64, 256, 0, stream>>>(bufA, fc1w_bf, fc1b, nullptr, bufR, 8192, 8192, 2048);
  // FC2 += into d_out
  gemm_bt_k<3><<<64 * 16, 256, 0, stream>>>(bufR, fc2w_bf, fc2b, nullptr, out, 8192, 2048, 8192);
}